// Round 3
// baseline (990.627 us; speedup 1.0000x reference)
//
#include <hip/hip_runtime.h>
#include <hip/hip_bf16.h>

// B=256, S=512, D=128, R=2048, H=0.5
#define Bn 256
#define Sn 512
#define Dn 128
#define Rn 2048
#define TB 32
#define NBLK (Sn / TB)   // 16 time-blocks
#define LDX 136          // Xin LDS row stride (bf16): 272 B -> +4 banks/row
#define LDP 2056         // PX LDS row stride (bf16): 4112 B -> +4 banks/row

using bf16_t = __hip_bfloat16;
typedef short bf16x8 __attribute__((ext_vector_type(8)));
typedef float f32x4 __attribute__((ext_vector_type(4)));
typedef float f32x2 __attribute__((ext_vector_type(2)));

__device__ __forceinline__ f32x2 clip2(f32x2 v) {
  v = __builtin_elementwise_max(v, (f32x2)(-5.f));
  v = __builtin_elementwise_min(v, (f32x2)(5.f));
  return v;
}

// fp32 -> bf16 bits, round-to-nearest-even (values are finite/clamped here).
__device__ __forceinline__ unsigned bf16rne(float f) {
  const unsigned u = __float_as_uint(f);
  return (u + 0x7fffu + ((u >> 16) & 1u)) >> 16;
}
__device__ __forceinline__ unsigned pack_bf16(f32x2 v) {
  return (bf16rne(v.y) << 16) | (bf16rne(v.x) & 0xffffu);
}

// K0: weights fp32->bf16, zero loss accumulators. Grid covers exactly Rn*Dn.
__global__ __launch_bounds__(256) void k_prep(const float* __restrict__ Wp,
                                              const float* __restrict__ Wr,
                                              bf16_t* __restrict__ Wp_b,
                                              bf16_t* __restrict__ Wr_b,
                                              float* __restrict__ losses) {
  const int i = blockIdx.x * 256 + threadIdx.x;
  Wp_b[i] = __float2bfloat16(Wp[i]);
  Wr_b[i] = __float2bfloat16(Wr[i]);
  if (i == 0) { losses[0] = 0.f; losses[1] = 0.f; }
}

// Fused pipeline: one workgroup per batch element b.
__global__ __launch_bounds__(256, 1) void k_fused(
    const float* __restrict__ inp,
    const float* __restrict__ om_i, const float* __restrict__ ga_i,
    const float* __restrict__ al_i,
    const bf16_t* __restrict__ Wp, const float* __restrict__ bp,
    const float* __restrict__ omr, const float* __restrict__ gar,
    const float* __restrict__ alr,
    const float* __restrict__ omo, const float* __restrict__ gao,
    const float* __restrict__ alo,
    const bf16_t* __restrict__ Wr, const float* __restrict__ br,
    float* __restrict__ preds, float* __restrict__ losses) {
  __shared__ bf16_t Xs[TB * LDX];    // 8.5 KB
  __shared__ bf16_t PX[TB * LDP];    // 128.5 KB (proj, overwritten by x_out in place)
  __shared__ float smi[4], smo[4];

  const int tid = threadIdx.x;
  const int b = blockIdx.x;
  const int wv = tid >> 6, lane = tid & 63;
  const int lr = lane & 15, lq = lane >> 4;

  // input oscillator state (threads 0..127 own d = tid)
  float xi = 0.f, yi = 0.f, pc_in = 0.f;
  float w2i = 0.f, g2i = 0.f, ai = 0.f;
  if (tid < Dn) {
    w2i = om_i[tid] * om_i[tid];
    g2i = 2.f * fabsf(ga_i[tid]);
    ai = al_i[tid];
  }
  const float* inpb = inp + (size_t)b * Sn * Dn;

  // reservoir/output oscillator state: thread owns r = tid*8 .. tid*8+7 (4 f32x2 pairs)
  const int r0 = tid * 8;
  f32x2 xr[4], yr[4], xo[4], yo[4];
  f32x2 w2r[4], g2r[4], arv[4], w2o[4], g2o[4], aov[4];
#pragma unroll
  for (int p = 0; p < 4; ++p) {
    f32x2 t;
    t = *(const f32x2*)(omr + r0 + 2 * p); w2r[p] = t * t;
    t = *(const f32x2*)(gar + r0 + 2 * p); g2r[p] = __builtin_elementwise_abs(t) * 2.f;
    arv[p] = *(const f32x2*)(alr + r0 + 2 * p);
    t = *(const f32x2*)(omo + r0 + 2 * p); w2o[p] = t * t;
    t = *(const f32x2*)(gao + r0 + 2 * p); g2o[p] = __builtin_elementwise_abs(t) * 2.f;
    aov[p] = *(const f32x2*)(alo + r0 + 2 * p);
    xr[p] = (f32x2)0.f; yr[p] = (f32x2)0.f;
    xo[p] = (f32x2)0.f; yo[p] = (f32x2)0.f;
  }
  f32x2 pc_out2 = (f32x2)0.f;

  for (int blk = 0; blk < NBLK; ++blk) {
    const int t0 = blk * TB;

    // ---- Phase A: input oscillator, 32 steps (threads 0..127) ----
    if (tid < Dn) {
      float fv[TB];
#pragma unroll
      for (int tt = 0; tt < TB; ++tt)
        fv[tt] = inpb[(size_t)(t0 + tt) * Dn + tid];
#pragma unroll
      for (int tt = 0; tt < TB; ++tt) {
        const float f = fv[tt];
        if (t0 + tt > 0) { const float e = xi - f; pc_in += e * e; }
        const float accel = ai * f - g2i * yi - w2i * xi;
        const float xn = fminf(fmaxf(xi + 0.5f * yi, -5.f), 5.f);
        const float yn = fminf(fmaxf(yi + 0.5f * accel, -5.f), 5.f);
        Xs[tt * LDX + tid] = __float2bfloat16(xn);
        xi = xn; yi = yn;
      }
    }
    __syncthreads();

    // ---- Phase B: proj tile [32 x 2048] = Xs[32x128] @ Wp^T, -> PX (bf16) ----
    {
      bf16x8 af[2][4];
#pragma unroll
      for (int i = 0; i < 2; ++i)
#pragma unroll
        for (int k = 0; k < 4; ++k)
          af[i][k] = *(const bf16x8*)&Xs[(i * 16 + lr) * LDX + k * 32 + lq * 8];

      const int n0w = wv * 512;  // wave's 512 r's
      const bf16_t* wp_base = Wp + (size_t)(n0w + lr) * Dn + lq * 8;
      bf16x8 bf[2][4];
#pragma unroll
      for (int k = 0; k < 4; ++k) {
        bf[0][k] = *(const bf16x8*)(wp_base + (size_t)0 * 16 * Dn + k * 32);
        bf[1][k] = *(const bf16x8*)(wp_base + (size_t)1 * 16 * Dn + k * 32);
      }
      for (int j = 0; j < 32; ++j) {
        const int pb = j & 1;
        f32x4 acc[2] = {(f32x4)0.f, (f32x4)0.f};
#pragma unroll
        for (int k = 0; k < 4; ++k) {
          acc[0] = __builtin_amdgcn_mfma_f32_16x16x32_bf16(af[0][k], bf[pb][k], acc[0], 0, 0, 0);
          acc[1] = __builtin_amdgcn_mfma_f32_16x16x32_bf16(af[1][k], bf[pb][k], acc[1], 0, 0, 0);
        }
        if (j + 2 < 32) {
#pragma unroll
          for (int k = 0; k < 4; ++k)
            bf[pb][k] = *(const bf16x8*)(wp_base + (size_t)(j + 2) * 16 * Dn + k * 32);
        }
        const int col = n0w + j * 16 + lr;
        const float bv = bp[col];
#pragma unroll
        for (int i = 0; i < 2; ++i)
#pragma unroll
          for (int r = 0; r < 4; ++r)
            PX[(i * 16 + lq * 4 + r) * LDP + col] = __float2bfloat16(acc[i][r] + bv);
      }
    }
    __syncthreads();

    // ---- Phase C: reservoir + output oscillators, in place in PX ----
    {
      uint4 pk = *(uint4*)&PX[0 * LDP + r0];
      for (int tt = 0; tt < TB; ++tt) {
        uint4 pk_n = pk;
        if (tt + 1 < TB) pk_n = *(uint4*)&PX[(tt + 1) * LDP + r0];
        const unsigned pw[4] = {pk.x, pk.y, pk.z, pk.w};
        unsigned okp[4];
#pragma unroll
        for (int p = 0; p < 4; ++p) {
          f32x2 pv;
          pv.x = __uint_as_float(pw[p] << 16);
          pv.y = __uint_as_float(pw[p] & 0xffff0000u);
          f32x2 acr = arv[p] * pv - g2r[p] * yr[p] - w2r[p] * xr[p];
          f32x2 xrn = clip2(xr[p] + yr[p] * 0.5f);
          f32x2 yrn = clip2(yr[p] + acr * 0.5f);
          f32x2 aco = aov[p] * xrn - g2o[p] * yo[p] - w2o[p] * xo[p];
          f32x2 xon = clip2(xo[p] + yo[p] * 0.5f);
          f32x2 yon = clip2(yo[p] + aco * 0.5f);
          f32x2 e = xon - xrn;
          pc_out2 += e * e;
          xr[p] = xrn; yr[p] = yrn; xo[p] = xon; yo[p] = yon;
          okp[p] = pack_bf16(xon);
        }
        uint4 ok;
        ok.x = okp[0]; ok.y = okp[1]; ok.z = okp[2]; ok.w = okp[3];
        *(uint4*)&PX[tt * LDP + r0] = ok;
        pk = pk_n;
      }
    }
    __syncthreads();

    // ---- Phase D: preds tile [32 x 128] = PX[32x2048] @ Wr^T + br -> global fp32 ----
    {
      const int d0w = wv * 32;  // wave's 32 d's
      const bf16_t* wr_base = Wr + (size_t)(d0w + lr) * Rn + lq * 8;
      f32x4 acc[2][2] = {{(f32x4)0.f, (f32x4)0.f}, {(f32x4)0.f, (f32x4)0.f}};
#pragma unroll 4
      for (int k0 = 0; k0 < Rn; k0 += 32) {
        bf16x8 a0 = *(const bf16x8*)&PX[(0 + lr) * LDP + k0 + lq * 8];
        bf16x8 a1 = *(const bf16x8*)&PX[(16 + lr) * LDP + k0 + lq * 8];
        bf16x8 b0 = *(const bf16x8*)(wr_base + k0);
        bf16x8 b1 = *(const bf16x8*)(wr_base + (size_t)16 * Rn + k0);
        acc[0][0] = __builtin_amdgcn_mfma_f32_16x16x32_bf16(a0, b0, acc[0][0], 0, 0, 0);
        acc[1][0] = __builtin_amdgcn_mfma_f32_16x16x32_bf16(a1, b0, acc[1][0], 0, 0, 0);
        acc[0][1] = __builtin_amdgcn_mfma_f32_16x16x32_bf16(a0, b1, acc[0][1], 0, 0, 0);
        acc[1][1] = __builtin_amdgcn_mfma_f32_16x16x32_bf16(a1, b1, acc[1][1], 0, 0, 0);
      }
      float* outb = preds + (size_t)b * Sn * Dn + (size_t)t0 * Dn;
#pragma unroll
      for (int jj = 0; jj < 2; ++jj) {
        const int col = d0w + jj * 16 + lr;
        const float bv = br[col];
#pragma unroll
        for (int i = 0; i < 2; ++i)
#pragma unroll
          for (int r = 0; r < 4; ++r)
            outb[(size_t)(i * 16 + lq * 4 + r) * Dn + col] = acc[i][jj][r] + bv;
      }
    }
    // no barrier needed here: next phase A only touches Xs; the post-A barrier
    // orders this phase's PX reads against next phase B's PX writes.
  }

  // ---- loss reduction: one atomicAdd per block per loss ----
  float vi = pc_in;
  float vo = pc_out2.x + pc_out2.y;
#pragma unroll
  for (int o = 32; o > 0; o >>= 1) {
    vi += __shfl_down(vi, o, 64);
    vo += __shfl_down(vo, o, 64);
  }
  __syncthreads();
  if (lane == 0) { smi[wv] = vi; smo[wv] = vo; }
  __syncthreads();
  if (tid == 0) {
    atomicAdd(losses + 0, (smi[0] + smi[1] + smi[2] + smi[3]) * (1.f / ((float)Bn * (float)Dn)));
    atomicAdd(losses + 1, (smo[0] + smo[1] + smo[2] + smo[3]) * (1.f / ((float)Bn * (float)Rn)));
  }
}

extern "C" void kernel_launch(void* const* d_in, const int* in_sizes, int n_in,
                              void* d_out, int out_size, void* d_ws, size_t ws_size,
                              hipStream_t stream) {
  const float* inputs    = (const float*)d_in[0];
  const float* omega_in  = (const float*)d_in[1];
  const float* gamma_in  = (const float*)d_in[2];
  const float* alpha_in  = (const float*)d_in[3];
  const float* W_proj    = (const float*)d_in[4];
  const float* b_proj    = (const float*)d_in[5];
  const float* omega_res = (const float*)d_in[6];
  const float* gamma_res = (const float*)d_in[7];
  const float* alpha_res = (const float*)d_in[8];
  const float* omega_out = (const float*)d_in[9];
  const float* gamma_out = (const float*)d_in[10];
  const float* alpha_out = (const float*)d_in[11];
  const float* W_read    = (const float*)d_in[12];
  const float* b_read    = (const float*)d_in[13];

  float* out = (float*)d_out;
  float* losses = out + (size_t)Bn * Sn * Dn;  // outputs concatenated: preds | pc_in | pc_out

  // ws: only 1 MB needed — bf16 copies of the two weight matrices.
  bf16_t* Wp_b = (bf16_t*)d_ws;
  bf16_t* Wr_b = Wp_b + (size_t)Rn * Dn;

  k_prep<<<1024, 256, 0, stream>>>(W_proj, W_read, Wp_b, Wr_b, losses);
  k_fused<<<Bn, 256, 0, stream>>>(inputs, omega_in, gamma_in, alpha_in,
                                  Wp_b, b_proj,
                                  omega_res, gamma_res, alpha_res,
                                  omega_out, gamma_out, alpha_out,
                                  Wr_b, b_read, out, losses);
}

// Round 4
// 782.192 us; speedup vs baseline: 1.2665x; 1.2665x over previous
//
#include <hip/hip_runtime.h>
#include <hip/hip_bf16.h>

// B=256, S=512, D=128, R=2048, H=0.5
#define Bn 256
#define Sn 512
#define Dn 128
#define Rn 2048
#define TB 32
#define NBLK (Sn / TB)   // 16 time-blocks
#define LDX 136          // Xs LDS row stride (bf16)
#define LDP 2056         // PX LDS row stride (bf16): 4112 B -> +4 banks/row
#define LDI 132          // input-stage LDS row stride (fp32)

using bf16_t = __hip_bfloat16;
typedef short bf16x8 __attribute__((ext_vector_type(8)));
typedef float f32x4 __attribute__((ext_vector_type(4)));
typedef float f32x2 __attribute__((ext_vector_type(2)));

__device__ __forceinline__ f32x2 clip2(f32x2 v) {
  v = __builtin_elementwise_max(v, (f32x2)(-5.f));
  v = __builtin_elementwise_min(v, (f32x2)(5.f));
  return v;
}

// fp32 -> bf16 bits, round-to-nearest-even (values finite/clamped here).
__device__ __forceinline__ unsigned bf16rne(float f) {
  const unsigned u = __float_as_uint(f);
  return (u + 0x7fffu + ((u >> 16) & 1u)) >> 16;
}
__device__ __forceinline__ unsigned pack_bf16(f32x2 v) {
  return (bf16rne(v.y) << 16) | (bf16rne(v.x) & 0xffffu);
}

// K0: weights fp32->bf16, zero loss accumulators. Grid covers exactly Rn*Dn.
__global__ __launch_bounds__(256) void k_prep(const float* __restrict__ Wp,
                                              const float* __restrict__ Wr,
                                              bf16_t* __restrict__ Wp_b,
                                              bf16_t* __restrict__ Wr_b,
                                              float* __restrict__ losses) {
  const int i = blockIdx.x * 256 + threadIdx.x;
  Wp_b[i] = __float2bfloat16(Wp[i]);
  Wr_b[i] = __float2bfloat16(Wr[i]);
  if (i == 0) { losses[0] = 0.f; losses[1] = 0.f; }
}

// Fused pipeline: one 512-thread workgroup (8 waves) per batch element b.
__global__ __launch_bounds__(512, 1) void k_fused(
    const float* __restrict__ inp,
    const float* __restrict__ om_i, const float* __restrict__ ga_i,
    const float* __restrict__ al_i,
    const bf16_t* __restrict__ Wp, const float* __restrict__ bp,
    const float* __restrict__ omr, const float* __restrict__ gar,
    const float* __restrict__ alr,
    const float* __restrict__ omo, const float* __restrict__ gao,
    const float* __restrict__ alo,
    const bf16_t* __restrict__ Wr, const float* __restrict__ br,
    float* __restrict__ preds, float* __restrict__ losses) {
  __shared__ bf16_t Xs[TB * LDX];    // 8.5 KB
  __shared__ bf16_t PX[TB * LDP];    // 128.5 KB (input stage / proj / x_out in place)
  __shared__ float bpS[Rn];          // 8 KB bias proj
  __shared__ float brS[Dn];          // 0.5 KB bias read
  __shared__ float smi[8], smo[8];

  const int tid = threadIdx.x;
  const int b = blockIdx.x;
  const int wv = tid >> 6, lane = tid & 63;
  const int lr = lane & 15, lq = lane >> 4;

  // bias preload (once)
#pragma unroll
  for (int i = tid; i < Rn; i += 512) bpS[i] = bp[i];
  if (tid < Dn) brS[tid] = br[tid];

  // input oscillator state (threads 0..127 own d = tid)
  float xi = 0.f, yi = 0.f, pc_in = 0.f;
  float w2i = 0.f, g2i = 0.f, ai = 0.f;
  if (tid < Dn) {
    w2i = om_i[tid] * om_i[tid];
    g2i = 2.f * fabsf(ga_i[tid]);
    ai = al_i[tid];
  }
  const float* inpb = inp + (size_t)b * Sn * Dn;

  // reservoir/output oscillator state: thread owns r = tid*4 .. tid*4+3 (2 f32x2 pairs)
  const int r0 = tid * 4;
  f32x2 xr[2], yr[2], xo[2], yo[2];
  f32x2 w2r[2], g2r[2], arv[2], w2o[2], g2o[2], aov[2];
#pragma unroll
  for (int p = 0; p < 2; ++p) {
    f32x2 t;
    t = *(const f32x2*)(omr + r0 + 2 * p); w2r[p] = t * t;
    t = *(const f32x2*)(gar + r0 + 2 * p); g2r[p] = __builtin_elementwise_abs(t) * 2.f;
    arv[p] = *(const f32x2*)(alr + r0 + 2 * p);
    t = *(const f32x2*)(omo + r0 + 2 * p); w2o[p] = t * t;
    t = *(const f32x2*)(gao + r0 + 2 * p); g2o[p] = __builtin_elementwise_abs(t) * 2.f;
    aov[p] = *(const f32x2*)(alo + r0 + 2 * p);
    xr[p] = (f32x2)0.f; yr[p] = (f32x2)0.f;
    xo[p] = (f32x2)0.f; yo[p] = (f32x2)0.f;
  }
  f32x2 pc_out2 = (f32x2)0.f;

  float* Is = (float*)PX;  // input staging overlay: [TB][LDI] fp32 = 16.9 KB

  __syncthreads();  // bpS/brS ready; PX free (first iteration)

  for (int blk = 0; blk < NBLK; ++blk) {
    const int t0 = blk * TB;

    // ---- Phase A0: cooperative input-tile stage -> Is (overlaid on PX) ----
    {
      const float* src = inpb + (size_t)t0 * Dn;
#pragma unroll
      for (int i = tid; i < (TB * Dn) / 4; i += 512) {
        const int row = i >> 5, c4 = (i & 31) * 4;
        *(f32x4*)&Is[row * LDI + c4] = *(const f32x4*)(src + (size_t)row * Dn + c4);
      }
    }
    __syncthreads();

    // ---- Phase A: input oscillator, 32 steps (threads 0..127) ----
    if (tid < Dn) {
#pragma unroll
      for (int tt = 0; tt < TB; ++tt) {
        const float f = Is[tt * LDI + tid];
        if (t0 + tt > 0) { const float e = xi - f; pc_in += e * e; }
        const float accel = ai * f - g2i * yi - w2i * xi;
        const float xn = fminf(fmaxf(xi + 0.5f * yi, -5.f), 5.f);
        const float yn = fminf(fmaxf(yi + 0.5f * accel, -5.f), 5.f);
        Xs[tt * LDX + tid] = __float2bfloat16(xn);
        xi = xn; yi = yn;
      }
    }
    __syncthreads();  // Xs ready; Is dead -> PX writable

    // ---- Phase B: proj tile [32 x 2048] = Xs[32x128] @ Wp^T -> PX (bf16) ----
    {
      bf16x8 af[2][4];
#pragma unroll
      for (int i = 0; i < 2; ++i)
#pragma unroll
        for (int k = 0; k < 4; ++k)
          af[i][k] = *(const bf16x8*)&Xs[(i * 16 + lr) * LDX + k * 32 + lq * 8];

      const int n0w = wv * 256;  // wave's 256 r's, 16 j-tiles
      const bf16_t* wp_base = Wp + (size_t)(n0w + lr) * Dn + lq * 8;
      bf16x8 bf[2][4];
#pragma unroll
      for (int k = 0; k < 4; ++k) {
        bf[0][k] = *(const bf16x8*)(wp_base + (size_t)0 * 16 * Dn + k * 32);
        bf[1][k] = *(const bf16x8*)(wp_base + (size_t)1 * 16 * Dn + k * 32);
      }
      for (int j = 0; j < 16; ++j) {
        const int pb = j & 1;
        f32x4 acc[2] = {(f32x4)0.f, (f32x4)0.f};
#pragma unroll
        for (int k = 0; k < 4; ++k) {
          acc[0] = __builtin_amdgcn_mfma_f32_16x16x32_bf16(af[0][k], bf[pb][k], acc[0], 0, 0, 0);
          acc[1] = __builtin_amdgcn_mfma_f32_16x16x32_bf16(af[1][k], bf[pb][k], acc[1], 0, 0, 0);
        }
        if (j + 2 < 16) {
#pragma unroll
          for (int k = 0; k < 4; ++k)
            bf[pb][k] = *(const bf16x8*)(wp_base + (size_t)(j + 2) * 16 * Dn + k * 32);
        }
        const int col = n0w + j * 16 + lr;
        const float bv = bpS[col];
#pragma unroll
        for (int i = 0; i < 2; ++i)
#pragma unroll
          for (int r = 0; r < 4; ++r)
            PX[(i * 16 + lq * 4 + r) * LDP + col] = __float2bfloat16(acc[i][r] + bv);
      }
    }
    __syncthreads();

    // ---- Phase C: reservoir + output oscillators, in place in PX ----
    {
      uint2 pk = *(uint2*)&PX[0 * LDP + r0];
      for (int tt = 0; tt < TB; ++tt) {
        uint2 pk_n = pk;
        if (tt + 1 < TB) pk_n = *(uint2*)&PX[(tt + 1) * LDP + r0];
        const unsigned pw[2] = {pk.x, pk.y};
        unsigned okp[2];
#pragma unroll
        for (int p = 0; p < 2; ++p) {
          f32x2 pv;
          pv.x = __uint_as_float(pw[p] << 16);
          pv.y = __uint_as_float(pw[p] & 0xffff0000u);
          f32x2 acr = arv[p] * pv - g2r[p] * yr[p] - w2r[p] * xr[p];
          f32x2 xrn = clip2(xr[p] + yr[p] * 0.5f);
          f32x2 yrn = clip2(yr[p] + acr * 0.5f);
          f32x2 aco = aov[p] * xrn - g2o[p] * yo[p] - w2o[p] * xo[p];
          f32x2 xon = clip2(xo[p] + yo[p] * 0.5f);
          f32x2 yon = clip2(yo[p] + aco * 0.5f);
          f32x2 e = xon - xrn;
          pc_out2 += e * e;
          xr[p] = xrn; yr[p] = yrn; xo[p] = xon; yo[p] = yon;
          okp[p] = pack_bf16(xon);
        }
        uint2 ok;
        ok.x = okp[0]; ok.y = okp[1];
        *(uint2*)&PX[tt * LDP + r0] = ok;
        pk = pk_n;
      }
    }
    __syncthreads();

    // ---- Phase D: preds tile [32 x 128] = PX[32x2048] @ Wr^T + br -> global fp32 ----
    {
      const int d0w = wv * 16;  // wave's 16 d's
      const bf16_t* wr_base = Wr + (size_t)(d0w + lr) * Rn + lq * 8;
      // even/odd K accumulators: 4 independent MFMA chains of 32
      f32x4 acc[2][2] = {{(f32x4)0.f, (f32x4)0.f}, {(f32x4)0.f, (f32x4)0.f}};
#pragma unroll 4
      for (int k0 = 0; k0 < Rn; k0 += 32) {
        const int par = (k0 >> 5) & 1;
        bf16x8 a0 = *(const bf16x8*)&PX[(0 + lr) * LDP + k0 + lq * 8];
        bf16x8 a1 = *(const bf16x8*)&PX[(16 + lr) * LDP + k0 + lq * 8];
        bf16x8 b0 = *(const bf16x8*)(wr_base + k0);
        acc[0][par] = __builtin_amdgcn_mfma_f32_16x16x32_bf16(a0, b0, acc[0][par], 0, 0, 0);
        acc[1][par] = __builtin_amdgcn_mfma_f32_16x16x32_bf16(a1, b0, acc[1][par], 0, 0, 0);
      }
      float* outb = preds + (size_t)b * Sn * Dn + (size_t)t0 * Dn;
      const int col = d0w + lr;
      const float bv = brS[col];
#pragma unroll
      for (int i = 0; i < 2; ++i) {
        f32x4 a = acc[i][0] + acc[i][1];
#pragma unroll
        for (int r = 0; r < 4; ++r)
          outb[(size_t)(i * 16 + lq * 4 + r) * Dn + col] = a[r] + bv;
      }
    }
    __syncthreads();  // PX reads done before next iteration's Is overlay write
  }

  // ---- loss reduction: one atomicAdd per block per loss ----
  float vi = pc_in;
  float vo = pc_out2.x + pc_out2.y;
#pragma unroll
  for (int o = 32; o > 0; o >>= 1) {
    vi += __shfl_down(vi, o, 64);
    vo += __shfl_down(vo, o, 64);
  }
  if (lane == 0) { smi[wv] = vi; smo[wv] = vo; }
  __syncthreads();
  if (tid == 0) {
    float si = 0.f, so = 0.f;
#pragma unroll
    for (int w = 0; w < 8; ++w) { si += smi[w]; so += smo[w]; }
    atomicAdd(losses + 0, si * (1.f / ((float)Bn * (float)Dn)));
    atomicAdd(losses + 1, so * (1.f / ((float)Bn * (float)Rn)));
  }
}

extern "C" void kernel_launch(void* const* d_in, const int* in_sizes, int n_in,
                              void* d_out, int out_size, void* d_ws, size_t ws_size,
                              hipStream_t stream) {
  const float* inputs    = (const float*)d_in[0];
  const float* omega_in  = (const float*)d_in[1];
  const float* gamma_in  = (const float*)d_in[2];
  const float* alpha_in  = (const float*)d_in[3];
  const float* W_proj    = (const float*)d_in[4];
  const float* b_proj    = (const float*)d_in[5];
  const float* omega_res = (const float*)d_in[6];
  const float* gamma_res = (const float*)d_in[7];
  const float* alpha_res = (const float*)d_in[8];
  const float* omega_out = (const float*)d_in[9];
  const float* gamma_out = (const float*)d_in[10];
  const float* alpha_out = (const float*)d_in[11];
  const float* W_read    = (const float*)d_in[12];
  const float* b_read    = (const float*)d_in[13];

  float* out = (float*)d_out;
  float* losses = out + (size_t)Bn * Sn * Dn;  // outputs concatenated: preds | pc_in | pc_out

  // ws: only 1 MB needed — bf16 copies of the two weight matrices.
  bf16_t* Wp_b = (bf16_t*)d_ws;
  bf16_t* Wr_b = Wp_b + (size_t)Rn * Dn;

  k_prep<<<1024, 256, 0, stream>>>(W_proj, W_read, Wp_b, Wr_b, losses);
  k_fused<<<Bn, 512, 0, stream>>>(inputs, omega_in, gamma_in, alpha_in,
                                  Wp_b, b_proj,
                                  omega_res, gamma_res, alpha_res,
                                  omega_out, gamma_out, alpha_out,
                                  Wr_b, b_read, out, losses);
}